// Round 7
// baseline (1029.890 us; speedup 1.0000x reference)
//
#include <hip/hip_runtime.h>
#include <hip/hip_bf16.h>

// Fenwick TreeLSTM, N=32768, D=256 — fused GEMM+cell.
// Round-7: counted-vmcnt 4-deep pipeline (T3+T4), never drain mid-loop.
//  r6 (passing, 984 µs) drained vmcnt(0) at EVERY K-step (__syncthreads):
//  in-flight bytes duty-cycle collapses -> latency-bound at 11% HBM BW,
//  ~10K cyc/step where compute needs ~1.5K. This round: BK=32, 4 circular
//  LDS buffers (4 x 18,432 B = 73,728 B, same footprint, 2 blocks/CU);
//  batch s+3 issued at iter s; end-of-iter waits vmcnt(2C) = "batch s+1
//  landed" (issued TWO iters ago); vmcnt(0) only at the tail.
//  Buffer safety: STAGE(iter s) targets buf[(s+3)&3], last read at iter s-1,
//  fenced by lgkmcnt(0)+sched_barrier(0) before barrier b(s-1) (rule 18).
//  Swizzle for 32-u16 rows: slot ^= (row>>1)&3, both sides -> <=2-way banks.
// Retained: popcount-parity state double-buffer (r6 race fix), XCD swizzle,
//  s_setprio around MFMA, packed first-touch-free phase-2 rows.

typedef unsigned short u16;
typedef unsigned int u32;
using short8  = __attribute__((ext_vector_type(8))) short;
using float4v = __attribute__((ext_vector_type(4))) float;

// ---- workspace layout (bytes) ----
// WmT  @ 0         : 1280x512 bf16 gate-permuted (1,310,720)
// WsT  @ 1310720   : 1280x512 bf16 gate-permuted (1,310,720)
// h0b  @ 2621440   : 32768x256 bf16 (16,777,216)
// hlv  @ 19398656  : levels 1..15 h bf16 (16,777,216)
// clv  @ 36175872  : levels 1..15 c fp32 (33,554,432)
// sthA @ 69730304  : state_h bf16, parity-0 buffer (16,777,216)
// sthB @ 86507520  : state_h bf16, parity-1 buffer (seeded) (16,777,216)
// total ~103.3 MB

__device__ __forceinline__ u16 f2bf(float f) {
  u32 u = __float_as_uint(f);
  u = (u + 0x7FFFu + ((u >> 16) & 1u)) >> 16;
  return (u16)u;
}
__device__ __forceinline__ float bf2f(u16 h) {
  return __uint_as_float(((u32)h) << 16);
}
__device__ __forceinline__ float sigf(float x) { return 1.0f / (1.0f + __expf(-x)); }
__device__ __forceinline__ float tanhfast(float x) {
  return 2.0f / (1.0f + __expf(-2.0f * x)) - 1.0f;
}

__device__ __forceinline__ void async16(const void* g, void* l) {
  __builtin_amdgcn_global_load_lds((const __attribute__((address_space(1))) void*)g,
                                   (__attribute__((address_space(3))) void*)l,
                                   16, 0, 0);
}

// A-row gather: row i of A = concat(hl(256 bf16), hr(256 bf16)).
// mode 1 takes PACKED row r (non-first-touch only): i = r + r/(2^k-1) + 1.
// State h for row t read from parity buffer buf[c&1], c = popcount(i & Dk).
__device__ __forceinline__ void row_srcs(int mode, int k, int row,
                                         const u16* h0b, const u16* hlv,
                                         const u16* sthA, const u16* sthB,
                                         const u16*& pL, const u16*& pR) {
  if (mode == 0) {
    const u16* pb = (k == 1) ? h0b : (hlv + (size_t)(32768 - (1 << (17 - k))) * 256);
    pL = pb + (size_t)(2 * row) * 256;
    pR = pb + (size_t)(2 * row + 1) * 256;
  } else {
    const int Dk = (1 << k) - 1;
    const int i = row + row / Dk + 1;
    const int t = ((i >> k) << (k + 1)) | (1 << k) | (i & Dk);
    const int c = __popc(i & Dk);            // touches so far (seed + gemms)
    const u16* sb = (c & 1) ? sthB : sthA;   // touch #c lives in buf[c&1]
    pL = sb + (size_t)(t - 1) * 256;
    const int idx = (t >> (k + 1)) * 2;
    pR = hlv + (size_t)((32768 - (1 << (16 - k))) + idx) * 256;
  }
}

// Fused GEMM + LSTM cell.
// Block tile: 128 rows x 160 cols (5 gates x 32 d), BK=32, 16 K-batches.
// 4 waves as 2(m) x 2(n): wave = 64 rows x 16 d's, acc[4 m-tiles][5 gates].
// LDS: 4 circular buffers x (A 128x32 + B 160x32 u16) = 4 x 18,432 B.
// Swizzle: 16B slot s_l holds global seg s_l ^ ((row>>1)&3)  [both sides].
__global__ __launch_bounds__(256) void gemm_cell(
    int mode, int k, int Mc,
    const u16* WT, const float* bias,
    const u16* h0b, const u16* hlv, u16* sthA, u16* sthB,
    const float* cpar, float* cout, u16* hout,
    const float* clv, float* out)
{
  __shared__ __align__(16) u16 smem[36864];   // 4 x 9216 u16
  const int tid  = threadIdx.x;
  const int lane = tid & 63;
  const int w    = tid >> 6;
  const int wm   = w >> 1, wn = w & 1;

  // XCD swizzle (bijective: grid is always a multiple of 8)
  const int nwg = gridDim.x;
  const int q8  = nwg >> 3;
  const int id  = (blockIdx.x & 7) * q8 + (blockIdx.x >> 3);
  const int bm  = id >> 3, bn = id & 7;

  // ---- A staging: 2 insts/wave; slot f=(w*2+j)*64+lane; row=f>>2; seg=f&3
  // global seg fetched = (f&3) ^ ((row>>1)&3) = (f&3) ^ ((f>>3)&3)
  const int f0 = w * 128 + lane;
  const int f1 = f0 + 64;
  int rl0 = bm * 128 + (f0 >> 2); if (rl0 > Mc - 1) rl0 = Mc - 1;
  int rl1 = bm * 128 + (f1 >> 2); if (rl1 > Mc - 1) rl1 = Mc - 1;
  const u16 *p0L, *p0R, *p1L, *p1R;
  row_srcs(mode, k, rl0, h0b, hlv, sthA, sthB, p0L, p0R);
  row_srcs(mode, k, rl1, h0b, hlv, sthA, sthB, p1L, p1R);
  const int sa0 = ((f0 & 3) ^ ((f0 >> 3) & 3)) * 8;
  const int sa1 = ((f1 & 3) ^ ((f1 >> 3) & 3)) * 8;

  // ---- B staging: 10 chunks of 16 rows; waves 0,1 take 3 chunks, 2,3 take 2
  // row n = ch*16 + (lane>>2); seg swz = (lane&3) ^ ((n>>1)&3) = ^ (lane>>3)&3
  const int ch0 = w, ch1 = 4 + w, ch2 = 8 + w;     // ch2 valid for w<2
  const int sb = ((lane & 3) ^ ((lane >> 3) & 3)) * 8;
  const u16* pB0 = WT + (size_t)(bn * 160 + ch0 * 16 + (lane >> 2)) * 512 + sb;
  const u16* pB1 = WT + (size_t)(bn * 160 + ch1 * 16 + (lane >> 2)) * 512 + sb;
  const u16* pB2 = (w < 2)
      ? WT + (size_t)(bn * 160 + ch2 * 16 + (lane >> 2)) * 512 + sb
      : pB0;

  float4v acc[4][5];
#pragma unroll
  for (int i = 0; i < 4; ++i)
#pragma unroll
    for (int j = 0; j < 5; ++j) acc[i][j] = (float4v){0.f, 0.f, 0.f, 0.f};

  const int mrow = lane & 15;
  const int kg   = lane >> 4;
  const int ks   = (kg ^ ((mrow >> 1) & 3)) * 8;   // swizzled 16B slot (read)
  const u16* aBase = smem + (wm * 64 + mrow) * 32 + ks;          // +mt*512 +cur*9216
  const u16* bBase = smem + 4096 + (wn * 16 + mrow) * 32 + ks;   // +g*1024 +cur*9216

  // stage K32-batch kk (0..15) into circular buffer buf (0..3).
  // Per wave: 2 A-insts + 2or3 B-insts, each 16 rows x 64B.
#define STAGE(buf, kk)                                                          \
  {                                                                             \
    const int co = ((kk) & 7) * 32;                                             \
    async16((((kk) < 8) ? p0L : p0R) + sa0 + co,                                \
            smem + (buf) * 9216 + (w * 2 + 0) * 512);                           \
    async16((((kk) < 8) ? p1L : p1R) + sa1 + co,                                \
            smem + (buf) * 9216 + (w * 2 + 1) * 512);                           \
    async16(pB0 + (kk) * 32, smem + (buf) * 9216 + 4096 + ch0 * 512);           \
    async16(pB1 + (kk) * 32, smem + (buf) * 9216 + 4096 + ch1 * 512);           \
    if (w < 2)                                                                  \
      async16(pB2 + (kk) * 32, smem + (buf) * 9216 + 4096 + ch2 * 512);         \
  }

  // prologue: 3 batches in flight; wait batch 0 (keep 2C outstanding)
  STAGE(0, 0); STAGE(1, 1); STAGE(2, 2);
  if (w < 2) { asm volatile("s_waitcnt vmcnt(10)" ::: "memory"); }
  else       { asm volatile("s_waitcnt vmcnt(8)"  ::: "memory"); }
  __builtin_amdgcn_s_barrier();

#pragma unroll
  for (int s = 0; s < 16; ++s) {
    const int cur = s & 3;
    if (s + 3 < 16) STAGE((s + 3) & 3, s + 3);    // buf freed by barrier b(s-1)
    short8 af[4], bfv[5];
    const u16* aB = aBase + cur * 9216;
    const u16* bB = bBase + cur * 9216;
#pragma unroll
    for (int mt = 0; mt < 4; ++mt) af[mt] = *(const short8*)(aB + mt * 512);
#pragma unroll
    for (int g = 0; g < 5; ++g)   bfv[g] = *(const short8*)(bB + g * 1024);
    asm volatile("s_waitcnt lgkmcnt(0)" ::: "memory");
    __builtin_amdgcn_sched_barrier(0);
    __builtin_amdgcn_s_setprio(1);
#pragma unroll
    for (int mt = 0; mt < 4; ++mt)
#pragma unroll
      for (int g = 0; g < 5; ++g)
        acc[mt][g] = __builtin_amdgcn_mfma_f32_16x16x32_bf16(af[mt], bfv[g], acc[mt][g], 0, 0, 0);
    __builtin_amdgcn_s_setprio(0);
    __builtin_amdgcn_sched_barrier(0);
    // counted wait: ensure batch s+1 landed; keep batches s+2,s+3 in flight
    if (s < 13) {
      if (w < 2) { asm volatile("s_waitcnt vmcnt(10)" ::: "memory"); }
      else       { asm volatile("s_waitcnt vmcnt(8)"  ::: "memory"); }
    } else if (s == 13) {
      if (w < 2) { asm volatile("s_waitcnt vmcnt(5)" ::: "memory"); }
      else       { asm volatile("s_waitcnt vmcnt(4)" ::: "memory"); }
    } else if (s == 14) {
      asm volatile("s_waitcnt vmcnt(0)" ::: "memory");
    }
    if (s < 15) __builtin_amdgcn_s_barrier();
  }
#undef STAGE

  // ---- fused cell epilogue ----
  // lane owns d = bn*32 + wn*16 + mrow; rows r0..r0+3 per m-tile.
  const int d = bn * 32 + wn * 16 + mrow;
  const float bi  = bias[d];
  const float bo_ = bias[256 + d];
  const float bu  = bias[512 + d];
  const float bfl = bias[768 + d];
  const float bfr2= bias[1024 + d];

#pragma unroll
  for (int mt = 0; mt < 4; ++mt) {
    const int r0 = bm * 128 + wm * 64 + mt * 16 + kg * 4;
#pragma unroll
    for (int r = 0; r < 4; ++r) {
      const int row = r0 + r;
      if (row >= Mc) continue;
      const float zi  = acc[mt][0][r] + bi;
      const float zo  = acc[mt][1][r] + bo_;
      const float zu  = acc[mt][2][r] + bu;
      const float zfl = acc[mt][3][r] + bfl;
      const float zfr = acc[mt][4][r] + bfr2;
      if (mode == 0) {
        const float cl = cpar[(size_t)(2 * row) * 256 + d];
        const float cr = cpar[(size_t)(2 * row + 1) * 256 + d];
        const float c = sigf(zi) * tanhfast(zu) + sigf(zfl) * cl + sigf(zfr) * cr;
        const float h = sigf(zo) * tanhfast(c);
        cout[(size_t)row * 256 + d] = c;
        hout[(size_t)row * 256 + d] = f2bf(h);
      } else {
        // packed row -> logical i; all rows are non-first-touch here
        const int Dk  = (1 << k) - 1;
        const int i   = row + row / Dk + 1;
        const int t   = ((i >> k) << (k + 1)) | (1 << k) | (i & Dk);
        const int lk  = 32768 - (1 << (16 - k));
        const int idx = (t >> (k + 1)) * 2;
        const float cr = clv[(size_t)(lk + idx) * 256 + d];
        const float cl = out[(size_t)(t - 1) * 512 + 256 + d];
        const float c = sigf(zi) * tanhfast(zu) + sigf(zfl) * cl + sigf(zfr) * cr;
        const float h = sigf(zo) * tanhfast(c);
        out[(size_t)(t - 1) * 512 + 256 + d] = c;
        if ((i >> k) == 0) {
          out[(size_t)(t - 1) * 512 + d] = h;  // k == MSB(t): final h
        } else {
          // touch #(c+1) -> buf[(c+1)&1]; read was buf[c&1] (never same)
          const int cpc = __popc(i & Dk);
          u16* dst = (cpc & 1) ? sthA : sthB;
          dst[(size_t)(t - 1) * 256 + d] = f2bf(h);
        }
      }
    }
  }
}

// k=0: odd t are first-touch copies of the leaves. Seed = touch #1 -> sthB.
__global__ __launch_bounds__(256) void copy_k0(
    const float* __restrict__ h_bot, const float* __restrict__ c_bot,
    float* __restrict__ out, u16* __restrict__ sthB)
{
  const int i = blockIdx.x;          // 0..16383
  const int d = threadIdx.x;
  const int t = 2 * i + 1;
  const float h = h_bot[(size_t)(t - 1) * 256 + d];
  const float c = c_bot[(size_t)(t - 1) * 256 + d];
  if (i == 0) out[(size_t)(t - 1) * 512 + d] = h;
  out[(size_t)(t - 1) * 512 + 256 + d] = c;
  sthB[(size_t)(t - 1) * 256 + d] = f2bf(h);
}

// Seed all even t (first touch at k = ctz(t)): state = level-k node.
// Seed = touch #1 -> sthB (non-pow2 t); pow2 t are final -> out h-half.
__global__ __launch_bounds__(256) void seed_even(
    const u16* __restrict__ hlv, const float* __restrict__ clv,
    float* __restrict__ out, u16* __restrict__ sthB)
{
  const int j = blockIdx.x;            // 0..16383
  const int t = 2 * j + 2;
  const int d = threadIdx.x;
  const int k = __ffs(t) - 1;          // >= 1
  const int lk = 32768 - (1 << (16 - k));
  const int nidx = (t >> (k + 1)) * 2;
  const u16 hb  = hlv[(size_t)(lk + nidx) * 256 + d];
  const float c = clv[(size_t)(lk + nidx) * 256 + d];
  out[(size_t)(t - 1) * 512 + 256 + d] = c;
  if ((t & (t - 1)) == 0) {
    out[(size_t)(t - 1) * 512 + d] = bf2f(hb);
  } else {
    sthB[(size_t)(t - 1) * 256 + d] = hb;
  }
}

// W (512x1280 fp32) -> gate-permuted W^T (1280x512 bf16).
__global__ __launch_bounds__(256) void transpose_w(
    const float* __restrict__ W, u16* __restrict__ WT)
{
  const int n = blockIdx.x;          // 0..1279 (permuted)
  const int b = n / 160, r = n % 160;
  const int g = r / 32,  dl = r % 32;
  const int col = g * 256 + b * 32 + dl;
  const int tid = threadIdx.x;       // 0..255
  WT[(size_t)n * 512 + tid]       = f2bf(W[(size_t)tid * 1280 + col]);
  WT[(size_t)n * 512 + tid + 256] = f2bf(W[(size_t)(tid + 256) * 1280 + col]);
}

__global__ __launch_bounds__(256) void cast_h0(
    const float* __restrict__ h, u16* __restrict__ h0b)
{
  const size_t i = (size_t)blockIdx.x * 256 + threadIdx.x;
  h0b[i] = f2bf(h[i]);
}

extern "C" void kernel_launch(void* const* d_in, const int* in_sizes, int n_in,
                              void* d_out, int out_size, void* d_ws, size_t ws_size,
                              hipStream_t stream) {
  const float* h_bot = (const float*)d_in[0];
  const float* c_bot = (const float*)d_in[1];
  const float* Wm    = (const float*)d_in[2];
  const float* bmv   = (const float*)d_in[3];
  const float* Wsu   = (const float*)d_in[4];
  const float* bsv   = (const float*)d_in[5];
  float* out = (float*)d_out;
  char* ws = (char*)d_ws;

  u16*   WmT  = (u16*)(ws + 0);
  u16*   WsT  = (u16*)(ws + 1310720);
  u16*   h0b  = (u16*)(ws + 2621440);
  u16*   hlv  = (u16*)(ws + 19398656);
  float* clv  = (float*)(ws + 36175872);
  u16*   sthA = (u16*)(ws + 69730304);
  u16*   sthB = (u16*)(ws + 86507520);

  transpose_w<<<1280, 256, 0, stream>>>(Wm, WmT);
  transpose_w<<<1280, 256, 0, stream>>>(Wsu, WsT);
  cast_h0<<<32768, 256, 0, stream>>>(h_bot, h0b);

  // ---- phase 1: build tree levels (fused; race-free, disjoint levels) ----
  for (int kl = 1; kl <= 15; ++kl) {
    const int M = 32768 >> kl;
    const float* cpar = (kl == 1) ? c_bot : (clv + (size_t)(32768 - (1 << (17 - kl))) * 256);
    float* cout = clv + (size_t)(32768 - (1 << (16 - kl))) * 256;
    u16*   hout = hlv + (size_t)(32768 - (1 << (16 - kl))) * 256;
    const int nbm = (M + 127) / 128;
    gemm_cell<<<nbm * 8, 256, 0, stream>>>(0, kl, M, WmT, bmv, h0b, hlv,
                                           sthA, sthB,
                                           cpar, cout, hout, clv, out);
  }

  // ---- phase 2: Fenwick accumulation (parity buffers, no merges) ----
  copy_k0<<<16384, 256, 0, stream>>>(h_bot, c_bot, out, sthB);
  seed_even<<<16384, 256, 0, stream>>>(hlv, clv, out, sthB);
  for (int kl = 1; kl <= 14; ++kl) {
    const int M = 16384 - (16384 >> kl);   // non-first-touch rows only
    const int nbm = (M + 127) / 128;
    gemm_cell<<<nbm * 8, 256, 0, stream>>>(1, kl, M, WsT, bsv, h0b, hlv,
                                           sthA, sthB,
                                           nullptr, nullptr, nullptr, clv, out);
  }
}